// Round 1
// 658.547 us; speedup vs baseline: 1.0202x; 1.0202x over previous
//
#include <hip/hip_runtime.h>

#define T_DIM 8
#define M_DIM 16384
#define K_DIM 128
#define N_DIM 1024

typedef __attribute__((ext_vector_type(8))) short bf16x8_t;
typedef __attribute__((ext_vector_type(4))) float f32x4_t;

__device__ __forceinline__ unsigned short f2bf(float f) {
  unsigned int v;
  __builtin_memcpy(&v, &f, 4);
  v += 0x7FFFu + ((v >> 16) & 1u);  // round-to-nearest-even
  return (unsigned short)(v >> 16);
}

// tanh-form gelu: g = x * t/(t+1), t = exp2(2*sqrt(2/pi)*log2(e)*(x+0.044715 x^3))
// max abs err vs exact erf-gelu ~3e-4. Clamp the nonlinear arg so t stays finite.
__device__ __forceinline__ float gelu_tanh(float x) {
  float xc = fminf(fmaxf(x, -8.f), 8.f);
  float y = 2.3022144f * __builtin_fmaf(0.044715f * xc * xc, xc, xc);
  float t = __builtin_amdgcn_exp2f(y);
  return x * t * __builtin_amdgcn_rcpf(t + 1.0f);
}

// W[t][k][n] fp32 -> WT[t][n][k] bf16, so the GEMM's B operand is k-contiguous.
__global__ __launch_bounds__(256) void transpose_w(
    const float* __restrict__ W, unsigned short* __restrict__ WT) {
  __shared__ __align__(16) unsigned short tile[64][72];
  int b = blockIdx.x;  // 8 t * 2 kt * 16 nt = 256 blocks
  int t = b >> 5;
  int r = b & 31;
  int kt = r >> 4;  // 0..1
  int nt = r & 15;  // 0..15
  int tid = threadIdx.x;
  const float* src =
      W + (size_t)t * (K_DIM * N_DIM) + (size_t)(kt * 64) * N_DIM + nt * 64;
#pragma unroll
  for (int it = 0; it < 4; ++it) {
    int li = it * 256 + tid;  // 0..1023
    int k = li >> 4;          // 0..63
    int c = li & 15;          // 0..15 (4-float chunks)
    float4 v = *(const float4*)(src + (size_t)k * N_DIM + c * 4);
    unsigned short u[4] = {f2bf(v.x), f2bf(v.y), f2bf(v.z), f2bf(v.w)};
    *(uint2*)&tile[k][c * 4] = *(const uint2*)u;  // 8 B, aligned (row stride 144 B)
  }
  __syncthreads();
  unsigned short* dst =
      WT + (size_t)t * (N_DIM * K_DIM) + (size_t)(nt * 64) * K_DIM + kt * 64;
#pragma unroll
  for (int it = 0; it < 2; ++it) {
    int li = it * 256 + tid;  // 0..511
    int n = li >> 3;          // 0..63
    int ck = li & 7;          // 0..7
    __align__(16) unsigned short tmp[8];
#pragma unroll
    for (int j = 0; j < 8; ++j) tmp[j] = tile[ck * 8 + j][n];
    *(uint4*)(dst + (size_t)n * K_DIM + ck * 8) = *(const uint4*)tmp;
  }
}

// Per block: 64 rows x ALL 1024 cols of batch t -> A fetched from HBM exactly
// once (structural reuse, not cache-dependent). W^T bf16 (256 KiB/t) is read
// per-fragment straight from L2; no B staging, one barrier per block.
// MFMA operands are SWAPPED (bf as A-operand, af as B-operand) so the D
// register quad runs along n: col = lane&15 -> m, row = (lane>>4)*4+rr -> n
// [m89/m91 layout, operand-swapped]. Each lane then stores a dense float4.
// 4 waves split N into 4x32; per wave per nb-chunk(128n): acc[4][2] 16x16 tiles.
__global__ __launch_bounds__(256, 3) void gemm_bias_gelu(
    const float* __restrict__ A,             // [T][M][K] fp32
    const unsigned short* __restrict__ WT,   // [T][N][K] bf16
    const float* __restrict__ bias,          // [T][N] fp32
    float* __restrict__ O) {                 // [T][M][N] fp32
  constexpr int BM = 64;
  constexpr int LDT = 136;  // 128 + 8 pad halves: row stride 272 B == 4 banks
                            // mod 32 -> b128 frag reads stay at the 8/bank
                            // baseline (no above-baseline conflicts)
  __shared__ __align__(16) unsigned short sA[BM * LDT];  // 17408 B -> LDS never
                                                         // limits occupancy

  int bid = blockIdx.x;  // 2048 = 8 t * 256 mt; t-major so concurrent blocks
                         // share one 256 KiB WT slice per XCD L2
  int t = bid >> 8;
  int mt = bid & 255;
  int tid = threadIdx.x;
  int lane = tid & 63;
  int wn = tid >> 6;   // wave id = n-quadrant (each wave owns 32 of 128 cols)
  int qk = lane >> 4;  // 0..3
  int lr = lane & 15;  // 0..15

  // ---- stage A once: 64 rows x 128 k fp32 -> bf16 LDS
  const float* Ag =
      A + (size_t)t * ((size_t)M_DIM * K_DIM) + (size_t)(mt * BM) * K_DIM;
#pragma unroll
  for (int it = 0; it < 8; ++it) {
    int li = it * 256 + tid;  // 0..2047
    int row = li >> 5;        // 0..63
    int c = li & 31;          // 0..31 (4-float chunks)
    float4 va = *(const float4*)(Ag + (size_t)row * K_DIM + c * 4);
    unsigned short u[4] = {f2bf(va.x), f2bf(va.y), f2bf(va.z), f2bf(va.w)};
    *(uint2*)&sA[row * LDT + c * 4] = *(const uint2*)u;
  }
  __syncthreads();  // the only barrier in the kernel

  const unsigned short* Bg = WT + (size_t)t * (N_DIM * K_DIM);
  const float* bg = bias + t * N_DIM;
  float* Og = O + (size_t)t * ((size_t)M_DIM * N_DIM) +
              (size_t)(mt * BM) * N_DIM;

#pragma unroll 1  // keep I-cache/regs bounded; TLP (12-20 waves/CU) hides L2 lat
  for (int nb = 0; nb < 8; ++nb) {
    int n0 = nb * 128 + wn * 32;

    // B fragments straight from L2: 8 x dwordx4, 16 rows x 64 B segments
    bf16x8_t bf[2][4];
#pragma unroll
    for (int j = 0; j < 2; ++j)
#pragma unroll
      for (int kk = 0; kk < 4; ++kk)
        bf[j][kk] = *(const bf16x8_t*)(Bg + (size_t)(n0 + j * 16 + lr) * K_DIM +
                                       kk * 32 + qk * 8);

    f32x4_t acc[4][2];
#pragma unroll
    for (int i = 0; i < 4; ++i)
#pragma unroll
      for (int j = 0; j < 2; ++j) acc[i][j] = (f32x4_t){0.f, 0.f, 0.f, 0.f};

#pragma unroll
    for (int kk = 0; kk < 4; ++kk) {
      bf16x8_t af[4];
#pragma unroll
      for (int i = 0; i < 4; ++i)
        af[i] = *(const bf16x8_t*)&sA[(i * 16 + lr) * LDT + kk * 32 + qk * 8];
#pragma unroll
      for (int i = 0; i < 4; ++i)
#pragma unroll
        for (int j = 0; j < 2; ++j)
          // swapped operands: D[r=n][c=m] = sum_k WT[n][k] * A[m][k]
          acc[i][j] = __builtin_amdgcn_mfma_f32_16x16x32_bf16(bf[j][kk], af[i],
                                                              acc[i][j], 0, 0, 0);
    }

    // ---- epilogue: bias + gelu, dense float4 nontemporal stores.
    // Lane -> m = i*16 + lr (col), n = n0 + j*16 + qk*4 + rr (row regs).
    // Per instr: 16 rows x 64 B segments; j=0/1 fill adjacent half-lines.
#pragma unroll
    for (int j = 0; j < 2; ++j) {
      f32x4_t bv = *(const f32x4_t*)(bg + n0 + j * 16 + qk * 4);
#pragma unroll
      for (int i = 0; i < 4; ++i) {
        f32x4_t o;
#pragma unroll
        for (int rr = 0; rr < 4; ++rr) o[rr] = gelu_tanh(acc[i][j][rr] + bv[rr]);
        __builtin_nontemporal_store(
            o, (f32x4_t*)(Og + (size_t)(i * 16 + lr) * N_DIM + n0 + j * 16 +
                          qk * 4));
      }
    }
  }
}

extern "C" void kernel_launch(void* const* d_in, const int* in_sizes, int n_in,
                              void* d_out, int out_size, void* d_ws, size_t ws_size,
                              hipStream_t stream) {
  const float* A = (const float*)d_in[0];     // inputs  [8,1,16384,128] fp32
  const float* W = (const float*)d_in[1];     // weights [8,1,128,1024] fp32
  const float* bias = (const float*)d_in[2];  // biases  [8,1,1,1024] fp32
  float* O = (float*)d_out;                   // [8,1,16384,1024] fp32
  unsigned short* WT = (unsigned short*)d_ws; // 2 MiB scratch: W^T in bf16

  transpose_w<<<256, 256, 0, stream>>>(W, WT);
  gemm_bias_gelu<<<2048, 256, 0, stream>>>(A, WT, bias, O);
}

// Round 2
// 617.909 us; speedup vs baseline: 1.0873x; 1.0658x over previous
//
#include <hip/hip_runtime.h>

#define T_DIM 8
#define M_DIM 16384
#define K_DIM 128
#define N_DIM 1024

typedef __attribute__((ext_vector_type(8))) short bf16x8_t;
typedef __attribute__((ext_vector_type(4))) float f32x4_t;

__device__ __forceinline__ unsigned short f2bf(float f) {
  unsigned int v;
  __builtin_memcpy(&v, &f, 4);
  v += 0x7FFFu + ((v >> 16) & 1u);  // round-to-nearest-even
  return (unsigned short)(v >> 16);
}

// tanh-form gelu: g = x * t/(t+1), t = exp2(2*sqrt(2/pi)*log2(e)*(x+0.044715 x^3))
// max abs err vs exact erf-gelu ~3e-4. Clamp the nonlinear arg so t stays finite.
__device__ __forceinline__ float gelu_tanh(float x) {
  float xc = fminf(fmaxf(x, -8.f), 8.f);
  float y = 2.3022144f * __builtin_fmaf(0.044715f * xc * xc, xc, xc);
  float t = __builtin_amdgcn_exp2f(y);
  return x * t * __builtin_amdgcn_rcpf(t + 1.0f);
}

// W[t][k][n] fp32 -> WT[t][n][k] bf16, so the GEMM's B operand is k-contiguous.
__global__ __launch_bounds__(256) void transpose_w(
    const float* __restrict__ W, unsigned short* __restrict__ WT) {
  __shared__ __align__(16) unsigned short tile[64][72];
  int b = blockIdx.x;  // 8 t * 2 kt * 16 nt = 256 blocks
  int t = b >> 5;
  int r = b & 31;
  int kt = r >> 4;  // 0..1
  int nt = r & 15;  // 0..15
  int tid = threadIdx.x;
  const float* src =
      W + (size_t)t * (K_DIM * N_DIM) + (size_t)(kt * 64) * N_DIM + nt * 64;
#pragma unroll
  for (int it = 0; it < 4; ++it) {
    int li = it * 256 + tid;  // 0..1023
    int k = li >> 4;          // 0..63
    int c = li & 15;          // 0..15 (4-float chunks)
    float4 v = *(const float4*)(src + (size_t)k * N_DIM + c * 4);
    unsigned short u[4] = {f2bf(v.x), f2bf(v.y), f2bf(v.z), f2bf(v.w)};
    *(uint2*)&tile[k][c * 4] = *(const uint2*)u;  // 8 B, aligned (row stride 144 B)
  }
  __syncthreads();
  unsigned short* dst =
      WT + (size_t)t * (N_DIM * K_DIM) + (size_t)(nt * 64) * K_DIM + kt * 64;
#pragma unroll
  for (int it = 0; it < 2; ++it) {
    int li = it * 256 + tid;  // 0..511
    int n = li >> 3;          // 0..63
    int ck = li & 7;          // 0..7
    __align__(16) unsigned short tmp[8];
#pragma unroll
    for (int j = 0; j < 8; ++j) tmp[j] = tile[ck * 8 + j][n];
    *(uint4*)(dst + (size_t)n * K_DIM + ck * 8) = *(const uint4*)tmp;
  }
}

// Per block: 64 rows x ALL 1024 cols of batch t -> A fetched from HBM exactly
// once. W^T bf16 (256 KiB/t) read per-fragment straight from L2.
// MFMA operands SWAPPED (bf as A-operand, af as B-operand) so the D register
// quad runs along n. NEW (R2): epilogue stages each 64x128 fp32 chunk through
// LDS and emits LINEAR stores -- each half-wave writes one row's 512 B dense
// (4 full 128 B lines), consecutive instrs walk consecutive rows. Theory: the
// old fragment-shaped stores (16 rows x 64 B @ 4 KB stride per instr) were
// the ~2 TB/s write bottleneck.
__global__ __launch_bounds__(256, 3) void gemm_bias_gelu(
    const float* __restrict__ A,             // [T][M][K] fp32
    const unsigned short* __restrict__ WT,   // [T][N][K] bf16
    const float* __restrict__ bias,          // [T][N] fp32
    float* __restrict__ O) {                 // [T][M][N] fp32
  constexpr int BM = 64;
  constexpr int LDT = 136;  // halves; 272 B row stride -> b128 reads at baseline
  constexpr int LDO = 132;  // floats; +4 pad -> staging write/read at baseline
  __shared__ __align__(16) unsigned short sA[BM * LDT];  // 17408 B
  __shared__ __align__(16) float sO[BM * LDO];           // 33792 B
  // total 51200 B -> 3 blocks/CU (153.6 KB of 160 KB)

  int bid = blockIdx.x;  // 2048 = 8 t * 256 mt; t-major so concurrent blocks
                         // share one 256 KiB WT slice per XCD L2
  int t = bid >> 8;
  int mt = bid & 255;
  int tid = threadIdx.x;
  int lane = tid & 63;
  int wn = tid >> 6;   // wave id = n-quadrant (each wave owns 32 of 128 cols)
  int qk = lane >> 4;  // 0..3
  int lr = lane & 15;  // 0..15

  // ---- stage A once: 64 rows x 128 k fp32 -> bf16 LDS
  const float* Ag =
      A + (size_t)t * ((size_t)M_DIM * K_DIM) + (size_t)(mt * BM) * K_DIM;
#pragma unroll
  for (int it = 0; it < 8; ++it) {
    int li = it * 256 + tid;  // 0..2047
    int row = li >> 5;        // 0..63
    int c = li & 31;          // 0..31 (4-float chunks)
    float4 va = *(const float4*)(Ag + (size_t)row * K_DIM + c * 4);
    unsigned short u[4] = {f2bf(va.x), f2bf(va.y), f2bf(va.z), f2bf(va.w)};
    *(uint2*)&sA[row * LDT + c * 4] = *(const uint2*)u;
  }
  __syncthreads();

  const unsigned short* Bg = WT + (size_t)t * (N_DIM * K_DIM);
  const float* bg = bias + t * N_DIM;
  float* Og = O + (size_t)t * ((size_t)M_DIM * N_DIM) +
              (size_t)(mt * BM) * N_DIM;

#pragma unroll 1  // keep I-cache/regs bounded; TLP hides L2 latency
  for (int nb = 0; nb < 8; ++nb) {
    int n0 = nb * 128 + wn * 32;

    // B fragments straight from L2: 8 x dwordx4, 16 rows x 64 B segments
    bf16x8_t bf[2][4];
#pragma unroll
    for (int j = 0; j < 2; ++j)
#pragma unroll
      for (int kk = 0; kk < 4; ++kk)
        bf[j][kk] = *(const bf16x8_t*)(Bg + (size_t)(n0 + j * 16 + lr) * K_DIM +
                                       kk * 32 + qk * 8);

    f32x4_t acc[4][2];
#pragma unroll
    for (int i = 0; i < 4; ++i)
#pragma unroll
      for (int j = 0; j < 2; ++j) acc[i][j] = (f32x4_t){0.f, 0.f, 0.f, 0.f};

#pragma unroll
    for (int kk = 0; kk < 4; ++kk) {
      bf16x8_t af[4];
#pragma unroll
      for (int i = 0; i < 4; ++i)
        af[i] = *(const bf16x8_t*)&sA[(i * 16 + lr) * LDT + kk * 32 + qk * 8];
#pragma unroll
      for (int i = 0; i < 4; ++i)
#pragma unroll
        for (int j = 0; j < 2; ++j)
          // swapped operands: D[r=n][c=m] = sum_k WT[n][k] * A[m][k]
          acc[i][j] = __builtin_amdgcn_mfma_f32_16x16x32_bf16(bf[j][kk], af[i],
                                                              acc[i][j], 0, 0, 0);
    }

    // ---- epilogue: bias + gelu in regs, stage to LDS, then linear stores.
    if (nb) __syncthreads();  // prior iteration's sO reads complete
#pragma unroll
    for (int j = 0; j < 2; ++j) {
      f32x4_t bv = *(const f32x4_t*)(bg + n0 + j * 16 + qk * 4);
#pragma unroll
      for (int i = 0; i < 4; ++i) {
        f32x4_t o;
#pragma unroll
        for (int rr = 0; rr < 4; ++rr) o[rr] = gelu_tanh(acc[i][j][rr] + bv[rr]);
        // lane -> m = i*16+lr, local n = wn*32 + j*16 + qk*4
        *(f32x4_t*)&sO[(i * 16 + lr) * LDO + wn * 32 + j * 16 + qk * 4] = o;
      }
    }
    __syncthreads();
    // linear stores: half-wave per row -> 512 B dense per row segment
#pragma unroll
    for (int p = 0; p < 8; ++p) {
      int row = p * 8 + (tid >> 5);  // 0..63
      int c = tid & 31;              // 0..31 (f32x4 chunks)
      f32x4_t v = *(const f32x4_t*)&sO[row * LDO + c * 4];
      __builtin_nontemporal_store(
          v, (f32x4_t*)(Og + (size_t)row * N_DIM + nb * 128 + c * 4));
    }
  }
}

extern "C" void kernel_launch(void* const* d_in, const int* in_sizes, int n_in,
                              void* d_out, int out_size, void* d_ws, size_t ws_size,
                              hipStream_t stream) {
  const float* A = (const float*)d_in[0];     // inputs  [8,1,16384,128] fp32
  const float* W = (const float*)d_in[1];     // weights [8,1,128,1024] fp32
  const float* bias = (const float*)d_in[2];  // biases  [8,1,1,1024] fp32
  float* O = (float*)d_out;                   // [8,1,16384,1024] fp32
  unsigned short* WT = (unsigned short*)d_ws; // 2 MiB scratch: W^T in bf16

  transpose_w<<<256, 256, 0, stream>>>(W, WT);
  gemm_bias_gelu<<<2048, 256, 0, stream>>>(A, WT, bias, O);
}